// Round 11
// baseline (403.024 us; speedup 1.0000x reference)
//
#include <hip/hip_runtime.h>

typedef _Float16 h2_t __attribute__((ext_vector_type(2)));
typedef _Float16 f16x8 __attribute__((ext_vector_type(8)));
typedef float f32x4 __attribute__((ext_vector_type(4)));
typedef unsigned u32x4 __attribute__((ext_vector_type(4)));

#define DI __device__ __forceinline__

#if __has_builtin(__builtin_amdgcn_sched_barrier)
#define SCHED_FENCE() __builtin_amdgcn_sched_barrier(0)
#else
#define SCHED_FENCE()
#endif

constexpr int PAW = 96;          // xt pitch (halfs): 192 B rows, 16B-aligned + XOR swizzle
constexpr int PBV = 72;          // hb pitch (halfs): 144 B rows = 9*16 -> b128-aligned
constexpr int TILE = 64 * PAW;   // one staged image plane: 6144 halfs
constexpr int PLANE = 64 * PBV;  // one hb plane: 4608 halfs
constexpr float kC1 = 1.0e-4f;   // (0.01*1)^2
constexpr float kC2 = 9.0e-4f;   // (0.03*1)^2
constexpr float kALPHA = 0.025f;

DI float rcp_fast(float v) { return __builtin_amdgcn_rcpf(v); }

DI float fdot2f(h2_t a, h2_t b, float c) {
#if __has_builtin(__builtin_amdgcn_fdot2)
  return __builtin_amdgcn_fdot2(a, b, c, false);   // v_dot2_f32_f16
#else
  return c + (float)(a.x) * (float)(b.x) + (float)(a.y) * (float)(b.y);
#endif
}

DI h2_t w2h(unsigned u) { return __builtin_bit_cast(h2_t, u); }

DI f16x8 ldfrag(const _Float16* __restrict__ p) {
  return *reinterpret_cast<const f16x8*>(p);
}

DI f32x4 mfma16(f16x8 a, f16x8 b, f32x4 c) {
  return __builtin_amdgcn_mfma_f32_16x16x32_f16(a, b, c, 0, 0, 0);
}

DI f16x8 pkabs8(f16x8 v) {
  u32x4 u = __builtin_bit_cast(u32x4, v);
  u32x4 msk = {0x7FFF7FFFu, 0x7FFF7FFFu, 0x7FFF7FFFu, 0x7FFF7FFFu};
  u &= msk;
  return __builtin_bit_cast(f16x8, u);
}

// ---- horizontal conv pass 1: fields {x, y, x^2+y^2} -> planes 0,1,2 ----
// D[col][row] = Wh(banded) x field^T.  nt outer, acc lifetime = one nt,
// store immediately + sched fence (R3 lesson: full unroll spills).
DI void hconv_p1(const _Float16* __restrict__ xt, _Float16* __restrict__ hb,
                 f16x8 wA0, f16x8 wA1, int w, int lane) {
  const int q = lane >> 4, m = lane & 15;
  const int K0b = (w < 2) ? 0 : 32;
  const int cb = w * 16 + q * 4;
  f32x4 zero4 = {0.f, 0.f, 0.f, 0.f};
#pragma unroll
  for (int nt = 0; nt < 4; ++nt) {
    const int row = nt * 16 + m;
    const int base = row * PAW + K0b + q * 8;
    f32x4 ax = zero4, ay = zero4, asq = zero4;
#pragma unroll
    for (int ks = 0; ks < 2; ++ks) {
      const f16x8 A = ks ? wA1 : wA0;
      const int idx = (base + ks * 32) ^ ((row & 7) << 3);
      f16x8 xv = ldfrag(xt + idx);
      f16x8 yv = ldfrag(xt + TILE + idx);
      ax = mfma16(A, xv, ax);
      ay = mfma16(A, yv, ay);
      asq = mfma16(A, xv * xv + yv * yv, asq);   // v_pk_mul/fma_f16
    }
    // C/D layout (m89-verified): m = (lane>>4)*4 + reg, n = lane&15.
    _Float16* wp = hb + cb * PBV + nt * 16 + m;
#pragma unroll
    for (int j = 0; j < 4; ++j) {
      wp[j * PBV] = (_Float16)ax[j];
      wp[PLANE + j * PBV] = (_Float16)ay[j];
      wp[2 * PLANE + j * PBV] = (_Float16)asq[j];
    }
    SCHED_FENCE();
  }
}

// ---- horizontal conv pass 2: {x*y} -> plane 0 (+ {|x-y|} -> plane 1 on LAST) ----
template<bool L1P>
DI void hconv_p2(const _Float16* __restrict__ xt, _Float16* __restrict__ hb,
                 f16x8 wA0, f16x8 wA1, int w, int lane) {
  const int q = lane >> 4, m = lane & 15;
  const int K0b = (w < 2) ? 0 : 32;
  const int cb = w * 16 + q * 4;
  f32x4 zero4 = {0.f, 0.f, 0.f, 0.f};
#pragma unroll
  for (int nt = 0; nt < 4; ++nt) {
    const int row = nt * 16 + m;
    const int base = row * PAW + K0b + q * 8;
    f32x4 axy = zero4, al1 = zero4;
#pragma unroll
    for (int ks = 0; ks < 2; ++ks) {
      const f16x8 A = ks ? wA1 : wA0;
      const int idx = (base + ks * 32) ^ ((row & 7) << 3);
      f16x8 xv = ldfrag(xt + idx);
      f16x8 yv = ldfrag(xt + TILE + idx);
      axy = mfma16(A, xv * yv, axy);
      if (L1P) al1 = mfma16(A, pkabs8(xv - yv), al1);
    }
    _Float16* wp = hb + cb * PBV + nt * 16 + m;
#pragma unroll
    for (int j = 0; j < 4; ++j) {
      wp[j * PBV] = (_Float16)axy[j];
      if (L1P) wp[PLANE + j * PBV] = (_Float16)al1[j];
    }
    SCHED_FENCE();
  }
}

// ---- vertical conv over NPL planes -> acc[2*pl+g] ----
// A = hb data (m = col, contiguous b128), B = weight frags (n = out-row group).
template<int NPL>
DI void vconvN(const _Float16* __restrict__ hb,
               f16x8 w00, f16x8 w01, f16x8 w10, f16x8 w11,
               int w, int lane, f32x4* __restrict__ acc) {
  const int q = lane >> 4, m = lane & 15;
  const int base = (w * 16 + m) * PBV + q * 8;
#pragma unroll
  for (int ks = 0; ks < 2; ++ks) {
    f16x8 B0 = ks ? w01 : w00;
    f16x8 B1 = ks ? w11 : w10;
#pragma unroll
    for (int pl = 0; pl < NPL; ++pl) {
      f16x8 A = ldfrag(hb + pl * PLANE + base + ks * 32);
      acc[2 * pl]     = mfma16(A, B0, acc[2 * pl]);
      acc[2 * pl + 1] = mfma16(A, B1, acc[2 * pl + 1]);
    }
    SCHED_FENCE();
  }
}

// ---- vertical conv of |x-y| (plane 1) collapsed to scalar via uniform U ----
DI float vl1(const _Float16* __restrict__ hb, const unsigned* __restrict__ U,
             int col, int r0) {
  const _Float16* p0 = hb + PLANE + col * PBV + r0;
  float s = 0.f;
#pragma unroll
  for (int p = 0; p < 20; ++p)
    s = fdot2f(w2h(U[p]), *reinterpret_cast<const h2_t*>(p0 + 2 * p), s);
  return s;
}

// Per sigma: p1{x,y,sq} | bar | vconv3 | bar | p2{xy(,l1)} | bar | vconv1 +
// fold (+vl1) | bar.  3 hb planes (51 KB total LDS) -> 3 blocks/CU: the extra
// 2 barriers/sigma are hidden by cross-block TLP (R10 showed 2 blocks/CU left
// ~45% of cycles as barrier/dependency stalls).  mux/muy/s2 (24 VGPR) live
// across p2 -- fine, the scratch-spill theory was disproven in R10.
template<bool LAST>
DI void do_sigma_m(int s, const _Float16* __restrict__ frh,
                   const unsigned* __restrict__ U,
                   const _Float16* __restrict__ xt, _Float16* __restrict__ hb,
                   float* __restrict__ PIcs, float& gl1s, int tid) {
  const int lane = tid & 63, w = tid >> 6;
  // weight frags [s][cls][ks][lane][8h]: shared between hconv (cls = w&1) and
  // vconv (cls = out-row group) because Delta0 = 32ks - 16cls in both.
  const f16x8* fr = reinterpret_cast<const f16x8*>(frh) + s * 256 + lane;
  f16x8 w00 = fr[0], w01 = fr[64], w10 = fr[128], w11 = fr[192];
  const bool odd = (w & 1);
  f16x8 wA0 = odd ? w10 : w00;
  f16x8 wA1 = odd ? w11 : w01;

  f32x4 zero4 = {0.f, 0.f, 0.f, 0.f};

  hconv_p1(xt, hb, wA0, wA1, w, lane);
  __syncthreads();
  f32x4 a1[6];                 // [0..1]=mux, [2..3]=muy, [4..5]=s2
#pragma unroll
  for (int i = 0; i < 6; ++i) a1[i] = zero4;
  vconvN<3>(hb, w00, w01, w10, w11, w, lane, a1);
  __syncthreads();
  hconv_p2<LAST>(xt, hb, wA0, wA1, w, lane);
  __syncthreads();
  f32x4 a2[2];                 // [0..1]=exy
  a2[0] = zero4; a2[1] = zero4;
  vconvN<1>(hb, w00, w01, w10, w11, w, lane, a2);
  if (LAST) gl1s += vl1(hb, U, lane, w * 8);
  // fold
#pragma unroll
  for (int h = 0; h < 2; ++h)
#pragma unroll
    for (int j = 0; j < 4; ++j) {
      const int i = h * 4 + j;
      float a = a1[h][j], b = a1[2 + h][j];
      float m2 = a * a + b * b, mxy = a * b;
      PIcs[i] *= fmaf(2.f, a2[h][j] - mxy, kC2) *
                 rcp_fast(a1[4 + h][j] - m2 + kC2);
      if (LAST)                            // luminance folded into PIcs
        PIcs[i] *= fmaf(2.f, mxy, kC1) * rcp_fast(m2 + kC1);
    }
  __syncthreads();                         // hb free for next sigma/channel
}

DI unsigned packh(float a, float b) {
  h2_t v; v.x = (_Float16)a; v.y = (_Float16)b;
  return __builtin_bit_cast(unsigned, v);
}

// ws layout (floats): [0..164] f32 1D kernels; u32 U[20] @168; weight frags
// (halfs) @208: [sigma][cls][ks][lane][8] = 10240 halfs (~20 KB).
__global__ void prep_k(const float* __restrict__ gm, float* __restrict__ ws) {
  int t = threadIdx.x;
  if (t < 165) {
    int s = t / 33, j = t % 33;
    const float* mk = gm + (3 * s) * (33 * 33);
    ws[t] = mk[16 * 33 + j] / sqrtf(mk[16 * 33 + 16]);
  }
  __syncthreads();
  if (t == 0) {
    // U[p] = sum over i=0..3, j=p-i in [0,16] of (E[j]+O[j]) halves, sigma=8
    const float* w = ws + 4 * 33;
    unsigned* U = (unsigned*)(ws + 168);
    for (int p = 0; p < 20; ++p) {
      float ux = 0.f, uy = 0.f;
      for (int i = 0; i < 4; ++i) {
        int j = p - i;
        if (j < 0 || j > 16) continue;
        ux += w[2 * j];
        if (2 * j + 1 <= 32) uy += w[2 * j + 1];
        if (j > 0) ux += w[2 * j - 1];
        uy += w[2 * j];
      }
      U[p] = packh(ux, uy);
    }
  }
  // weight fragments; k-map k = K0 + 8*(lane>>4) + i applied identically to the
  // data-operand reads, so any bijective mis-guess of the HW k-map cancels.
  _Float16* fr = (_Float16*)(ws + 208);
  const int Rs[5] = {4, 6, 12, 16, 16};
  for (int e = t; e < 10240; e += 256) {
    int s = e >> 11, r = e & 2047;
    int cls = (r >> 10) & 1, ks = (r >> 9) & 1, lane = (r >> 3) & 63, i = r & 7;
    int tp = 32 * ks - 16 * cls + 8 * (lane >> 4) + i - (lane & 15);
    int R = Rs[s], j = tp - 16 + R;
    float v = (j >= 0 && j <= 2 * R) ? ws[s * 33 + j] : 0.f;
    fr[e] = (_Float16)v;
  }
}

// 64x32 output tile, 3 hb planes: 51 KB LDS -> 3 blocks/CU (was 69.5 KB / 2).
// (256,3): VGPR cap ~170; compiler picked 128 at (256,2) so no squeeze expected.
__global__ __launch_bounds__(256, 3)
void msloss_k(const float* __restrict__ x, const float* __restrict__ y,
              const float* __restrict__ ws, float* __restrict__ out) {
  // xt @0 [row][col] swizzled (64x96), yt @TILE, hb @2*TILE: 3 planes [col][row]
  __shared__ __align__(16) _Float16 smem[2 * TILE + 3 * PLANE];
  __shared__ float red[4];
  _Float16* xt = smem;
  _Float16* hb = smem + 2 * TILE;
  const _Float16* frh = (const _Float16*)(ws + 208);
  const unsigned* U = (const unsigned*)(ws + 168);
  const int tid = threadIdx.x;
  const int ox = blockIdx.x * 64, oy = blockIdx.y * 32;
  const int b = blockIdx.z;

  float PIcs[8];
  float gl1s = 0.f;
#pragma unroll
  for (int i = 0; i < 8; ++i) PIcs[i] = 1.f;

  for (int c = 0; c < 3; ++c) {
    const float* xp = x + (size_t)(b * 3 + c) * (512 * 512);
    const float* yp = y + (size_t)(b * 3 + c) * (512 * 512);
    // stage 64 rows x 96 cols fp32 -> fp16, swizzled [row][col], zero halo
#pragma unroll
    for (int it = 0; it < 12; ++it) {
      int idx = it * 256 + tid;            // 64 rows x 48 colpairs
      int row = idx / 48, cp = idx % 48;
      int gy = oy + row - 16, gx = ox + cp * 2 - 16;
      bool ok = ((unsigned)gy < 512u) && ((unsigned)gx < 512u);  // gx even
      float2 xv = make_float2(0.f, 0.f), yv = make_float2(0.f, 0.f);
      if (ok) {
        xv = *reinterpret_cast<const float2*>(xp + gy * 512 + gx);
        yv = *reinterpret_cast<const float2*>(yp + gy * 512 + gx);
      }
      h2_t hx; hx.x = (_Float16)xv.x; hx.y = (_Float16)xv.y;
      h2_t hy; hy.x = (_Float16)yv.x; hy.y = (_Float16)yv.y;
      int si = (row * PAW + cp * 2) ^ ((row & 7) << 3);   // h2-safe: XOR bits>=3
      *reinterpret_cast<h2_t*>(xt + si) = hx;
      *reinterpret_cast<h2_t*>(xt + TILE + si) = hy;
    }
    __syncthreads();
    do_sigma_m<false>(0, frh, U, xt, hb, PIcs, gl1s, tid);
    do_sigma_m<false>(1, frh, U, xt, hb, PIcs, gl1s, tid);
    do_sigma_m<false>(2, frh, U, xt, hb, PIcs, gl1s, tid);
    do_sigma_m<false>(3, frh, U, xt, hb, PIcs, gl1s, tid);
    do_sigma_m<true >(4, frh, U, xt, hb, PIcs, gl1s, tid);
    // do_sigma ends with __syncthreads(): safe to restage next channel
  }

  float s = ((1.f - kALPHA) / 3.f) * gl1s;
#pragma unroll
  for (int i = 0; i < 8; ++i) s += kALPHA * (1.f - PIcs[i]);
#pragma unroll
  for (int off = 32; off > 0; off >>= 1) s += __shfl_down(s, off);
  if ((tid & 63) == 0) red[tid >> 6] = s;
  __syncthreads();
  if (tid == 0)
    atomicAdd(out, (red[0] + red[1] + red[2] + red[3]) *
                       (200.0f / (8.0f * 512.0f * 512.0f)));
}

extern "C" void kernel_launch(void* const* d_in, const int* in_sizes, int n_in,
                              void* d_out, int out_size, void* d_ws, size_t ws_size,
                              hipStream_t stream) {
  const float* x = (const float*)d_in[0];
  const float* y = (const float*)d_in[1];
  const float* gm = (const float*)d_in[2];
  float* out = (float*)d_out;
  float* ws = (float*)d_ws;   // 165 f32 + U + 20 KB weight frags

  hipMemsetAsync(d_out, 0, out_size * sizeof(float), stream);
  prep_k<<<1, 256, 0, stream>>>(gm, ws);
  msloss_k<<<dim3(8, 16, 8), 256, 0, stream>>>(x, y, ws, out);
}

// Round 14
// 298.467 us; speedup vs baseline: 1.3503x; 1.3503x over previous
//
#include <hip/hip_runtime.h>

typedef _Float16 h2_t __attribute__((ext_vector_type(2)));
typedef _Float16 f16x8 __attribute__((ext_vector_type(8)));
typedef float f32x4 __attribute__((ext_vector_type(4)));
typedef unsigned u32x4 __attribute__((ext_vector_type(4)));

#define DI __device__ __forceinline__

#if __has_builtin(__builtin_amdgcn_sched_barrier)
#define SCHED_FENCE() __builtin_amdgcn_sched_barrier(0)
#else
#define SCHED_FENCE()
#endif

constexpr int PAW = 96;          // xt pitch (halfs): 192 B rows, 16B-aligned + XOR swizzle
constexpr int PBV = 72;          // hb pitch (halfs): 144 B rows = 9*16 -> b128-aligned
constexpr int TILE = 64 * PAW;   // one staged image plane: 6144 halfs
constexpr int PLANE = 64 * PBV;  // one hb plane: 4608 halfs
constexpr float kC1 = 1.0e-4f;   // (0.01*1)^2
constexpr float kC2 = 9.0e-4f;   // (0.03*1)^2
constexpr float kALPHA = 0.025f;

DI float rcp_fast(float v) { return __builtin_amdgcn_rcpf(v); }

DI float fdot2f(h2_t a, h2_t b, float c) {
#if __has_builtin(__builtin_amdgcn_fdot2)
  return __builtin_amdgcn_fdot2(a, b, c, false);   // v_dot2_f32_f16
#else
  return c + (float)(a.x) * (float)(b.x) + (float)(a.y) * (float)(b.y);
#endif
}

DI h2_t w2h(unsigned u) { return __builtin_bit_cast(h2_t, u); }

DI f16x8 ldfrag(const _Float16* __restrict__ p) {
  return *reinterpret_cast<const f16x8*>(p);
}

DI f32x4 mfma16(f16x8 a, f16x8 b, f32x4 c) {
  return __builtin_amdgcn_mfma_f32_16x16x32_f16(a, b, c, 0, 0, 0);
}

DI f16x8 pkabs8(f16x8 v) {
  u32x4 u = __builtin_bit_cast(u32x4, v);
  u32x4 msk = {0x7FFF7FFFu, 0x7FFF7FFFu, 0x7FFF7FFFu, 0x7FFF7FFFu};
  u &= msk;
  return __builtin_bit_cast(f16x8, u);
}

// ---- horizontal conv pass 1: fields {x, y, x^2+y^2} -> planes 0,1,2 ----
// D[col][row] = Wh(banded) x field^T.  nt outer, acc lifetime = one nt,
// store immediately + sched fence (R3 lesson: full unroll spills).
DI void hconv_p1(const _Float16* __restrict__ xt, _Float16* __restrict__ hb,
                 f16x8 wA0, f16x8 wA1, int w, int lane) {
  const int q = lane >> 4, m = lane & 15;
  const int K0b = (w < 2) ? 0 : 32;
  const int cb = w * 16 + q * 4;
  f32x4 zero4 = {0.f, 0.f, 0.f, 0.f};
#pragma unroll
  for (int nt = 0; nt < 4; ++nt) {
    const int row = nt * 16 + m;
    const int base = row * PAW + K0b + q * 8;
    f32x4 ax = zero4, ay = zero4, asq = zero4;
#pragma unroll
    for (int ks = 0; ks < 2; ++ks) {
      const f16x8 A = ks ? wA1 : wA0;
      const int idx = (base + ks * 32) ^ ((row & 7) << 3);
      f16x8 xv = ldfrag(xt + idx);
      f16x8 yv = ldfrag(xt + TILE + idx);
      ax = mfma16(A, xv, ax);
      ay = mfma16(A, yv, ay);
      asq = mfma16(A, xv * xv + yv * yv, asq);   // v_pk_mul/fma_f16
    }
    // C/D layout (m89-verified): m = (lane>>4)*4 + reg, n = lane&15.
    _Float16* wp = hb + cb * PBV + nt * 16 + m;
#pragma unroll
    for (int j = 0; j < 4; ++j) {
      wp[j * PBV] = (_Float16)ax[j];
      wp[PLANE + j * PBV] = (_Float16)ay[j];
      wp[2 * PLANE + j * PBV] = (_Float16)asq[j];
    }
    SCHED_FENCE();
  }
}

// ---- horizontal conv pass 2: {x*y} -> plane 0 (+ {|x-y|} -> plane 1 on LAST) ----
template<bool L1P>
DI void hconv_p2(const _Float16* __restrict__ xt, _Float16* __restrict__ hb,
                 f16x8 wA0, f16x8 wA1, int w, int lane) {
  const int q = lane >> 4, m = lane & 15;
  const int K0b = (w < 2) ? 0 : 32;
  const int cb = w * 16 + q * 4;
  f32x4 zero4 = {0.f, 0.f, 0.f, 0.f};
#pragma unroll
  for (int nt = 0; nt < 4; ++nt) {
    const int row = nt * 16 + m;
    const int base = row * PAW + K0b + q * 8;
    f32x4 axy = zero4, al1 = zero4;
#pragma unroll
    for (int ks = 0; ks < 2; ++ks) {
      const f16x8 A = ks ? wA1 : wA0;
      const int idx = (base + ks * 32) ^ ((row & 7) << 3);
      f16x8 xv = ldfrag(xt + idx);
      f16x8 yv = ldfrag(xt + TILE + idx);
      axy = mfma16(A, xv * yv, axy);
      if (L1P) al1 = mfma16(A, pkabs8(xv - yv), al1);
    }
    _Float16* wp = hb + cb * PBV + nt * 16 + m;
#pragma unroll
    for (int j = 0; j < 4; ++j) {
      wp[j * PBV] = (_Float16)axy[j];
      if (L1P) wp[PLANE + j * PBV] = (_Float16)al1[j];
    }
    SCHED_FENCE();
  }
}

// ---- vertical conv over NPL planes -> acc[2*pl+g] ----
// A = hb data (m = col, contiguous b128), B = weight frags (n = out-row group).
template<int NPL>
DI void vconvN(const _Float16* __restrict__ hb,
               f16x8 w00, f16x8 w01, f16x8 w10, f16x8 w11,
               int w, int lane, f32x4* __restrict__ acc) {
  const int q = lane >> 4, m = lane & 15;
  const int base = (w * 16 + m) * PBV + q * 8;
#pragma unroll
  for (int ks = 0; ks < 2; ++ks) {
    f16x8 B0 = ks ? w01 : w00;
    f16x8 B1 = ks ? w11 : w10;
#pragma unroll
    for (int pl = 0; pl < NPL; ++pl) {
      f16x8 A = ldfrag(hb + pl * PLANE + base + ks * 32);
      acc[2 * pl]     = mfma16(A, B0, acc[2 * pl]);
      acc[2 * pl + 1] = mfma16(A, B1, acc[2 * pl + 1]);
    }
    SCHED_FENCE();
  }
}

// ---- vertical conv of |x-y| (plane 1) collapsed to scalar via uniform U ----
DI float vl1(const _Float16* __restrict__ hb, const unsigned* __restrict__ U,
             int col, int r0) {
  const _Float16* p0 = hb + PLANE + col * PBV + r0;
  float s = 0.f;
#pragma unroll
  for (int p = 0; p < 20; ++p)
    s = fdot2f(w2h(U[p]), *reinterpret_cast<const h2_t*>(p0 + 2 * p), s);
  return s;
}

// Per sigma: p1{x,y,sq} | bar | vconv3 | bar | p2{xy(,l1)} | bar | vconv1 +
// fold (+vl1) | bar.  3 hb planes -> 51.5 KB LDS -> 3 blocks/CU by HARDWARE
// occupancy math (LDS 160/51.5 = 3; VGPR 128 allows 4 waves/SIMD > the 3
// needed).  NOTE: do NOT use __launch_bounds__(256,3) -- twice measured (R2,
// R11) it makes the allocator cap at 84 VGPRs and spill ~300-700 MB of
// scratch (R11: WRITE 397 MB, dur 320 us).  (256,2) leaves the allocator at
// its natural ~128 and the 3rd block still fits.
template<bool LAST>
DI void do_sigma_m(int s, const _Float16* __restrict__ frh,
                   const unsigned* __restrict__ U,
                   const _Float16* __restrict__ xt, _Float16* __restrict__ hb,
                   float* __restrict__ PIcs, float& gl1s, int tid) {
  const int lane = tid & 63, w = tid >> 6;
  // weight frags [s][cls][ks][lane][8h]: shared between hconv (cls = w&1) and
  // vconv (cls = out-row group) because Delta0 = 32ks - 16cls in both.
  const f16x8* fr = reinterpret_cast<const f16x8*>(frh) + s * 256 + lane;
  f16x8 w00 = fr[0], w01 = fr[64], w10 = fr[128], w11 = fr[192];
  const bool odd = (w & 1);
  f16x8 wA0 = odd ? w10 : w00;
  f16x8 wA1 = odd ? w11 : w01;

  f32x4 zero4 = {0.f, 0.f, 0.f, 0.f};

  hconv_p1(xt, hb, wA0, wA1, w, lane);
  __syncthreads();
  f32x4 a1[6];                 // [0..1]=mux, [2..3]=muy, [4..5]=s2
#pragma unroll
  for (int i = 0; i < 6; ++i) a1[i] = zero4;
  vconvN<3>(hb, w00, w01, w10, w11, w, lane, a1);
  __syncthreads();
  hconv_p2<LAST>(xt, hb, wA0, wA1, w, lane);
  __syncthreads();
  f32x4 a2[2];                 // [0..1]=exy
  a2[0] = zero4; a2[1] = zero4;
  vconvN<1>(hb, w00, w01, w10, w11, w, lane, a2);
  if (LAST) gl1s += vl1(hb, U, lane, w * 8);
  // fold
#pragma unroll
  for (int h = 0; h < 2; ++h)
#pragma unroll
    for (int j = 0; j < 4; ++j) {
      const int i = h * 4 + j;
      float a = a1[h][j], b = a1[2 + h][j];
      float m2 = a * a + b * b, mxy = a * b;
      PIcs[i] *= fmaf(2.f, a2[h][j] - mxy, kC2) *
                 rcp_fast(a1[4 + h][j] - m2 + kC2);
      if (LAST)                            // luminance folded into PIcs
        PIcs[i] *= fmaf(2.f, mxy, kC1) * rcp_fast(m2 + kC1);
    }
  __syncthreads();                         // hb free for next sigma/channel
}

DI unsigned packh(float a, float b) {
  h2_t v; v.x = (_Float16)a; v.y = (_Float16)b;
  return __builtin_bit_cast(unsigned, v);
}

// ws layout (floats): [0..164] f32 1D kernels; u32 U[20] @168; weight frags
// (halfs) @208: [sigma][cls][ks][lane][8] = 10240 halfs (~20 KB).
__global__ void prep_k(const float* __restrict__ gm, float* __restrict__ ws) {
  int t = threadIdx.x;
  if (t < 165) {
    int s = t / 33, j = t % 33;
    const float* mk = gm + (3 * s) * (33 * 33);
    ws[t] = mk[16 * 33 + j] / sqrtf(mk[16 * 33 + 16]);
  }
  __syncthreads();
  if (t == 0) {
    // U[p] = sum over i=0..3, j=p-i in [0,16] of (E[j]+O[j]) halves, sigma=8
    const float* w = ws + 4 * 33;
    unsigned* U = (unsigned*)(ws + 168);
    for (int p = 0; p < 20; ++p) {
      float ux = 0.f, uy = 0.f;
      for (int i = 0; i < 4; ++i) {
        int j = p - i;
        if (j < 0 || j > 16) continue;
        ux += w[2 * j];
        if (2 * j + 1 <= 32) uy += w[2 * j + 1];
        if (j > 0) ux += w[2 * j - 1];
        uy += w[2 * j];
      }
      U[p] = packh(ux, uy);
    }
  }
  // weight fragments; k-map k = K0 + 8*(lane>>4) + i applied identically to the
  // data-operand reads, so any bijective mis-guess of the HW k-map cancels.
  _Float16* fr = (_Float16*)(ws + 208);
  const int Rs[5] = {4, 6, 12, 16, 16};
  for (int e = t; e < 10240; e += 256) {
    int s = e >> 11, r = e & 2047;
    int cls = (r >> 10) & 1, ks = (r >> 9) & 1, lane = (r >> 3) & 63, i = r & 7;
    int tp = 32 * ks - 16 * cls + 8 * (lane >> 4) + i - (lane & 15);
    int R = Rs[s], j = tp - 16 + R;
    float v = (j >= 0 && j <= 2 * R) ? ws[s * 33 + j] : 0.f;
    fr[e] = (_Float16)v;
  }
}

// 64x32 output tile, 3 hb planes: 51.5 KB LDS. (256,2): natural VGPR alloc
// (~128) -> HW fits 3 blocks/CU (LDS-capped), no 84-VGPR squeeze (see above).
__global__ __launch_bounds__(256, 2)
void msloss_k(const float* __restrict__ x, const float* __restrict__ y,
              const float* __restrict__ ws, float* __restrict__ out) {
  // xt @0 [row][col] swizzled (64x96), yt @TILE, hb @2*TILE: 3 planes [col][row]
  __shared__ __align__(16) _Float16 smem[2 * TILE + 3 * PLANE];
  __shared__ float red[4];
  _Float16* xt = smem;
  _Float16* hb = smem + 2 * TILE;
  const _Float16* frh = (const _Float16*)(ws + 208);
  const unsigned* U = (const unsigned*)(ws + 168);
  const int tid = threadIdx.x;
  const int ox = blockIdx.x * 64, oy = blockIdx.y * 32;
  const int b = blockIdx.z;

  float PIcs[8];
  float gl1s = 0.f;
#pragma unroll
  for (int i = 0; i < 8; ++i) PIcs[i] = 1.f;

  for (int c = 0; c < 3; ++c) {
    const float* xp = x + (size_t)(b * 3 + c) * (512 * 512);
    const float* yp = y + (size_t)(b * 3 + c) * (512 * 512);
    // stage 64 rows x 96 cols fp32 -> fp16, swizzled [row][col], zero halo
#pragma unroll
    for (int it = 0; it < 12; ++it) {
      int idx = it * 256 + tid;            // 64 rows x 48 colpairs
      int row = idx / 48, cp = idx % 48;
      int gy = oy + row - 16, gx = ox + cp * 2 - 16;
      bool ok = ((unsigned)gy < 512u) && ((unsigned)gx < 512u);  // gx even
      float2 xv = make_float2(0.f, 0.f), yv = make_float2(0.f, 0.f);
      if (ok) {
        xv = *reinterpret_cast<const float2*>(xp + gy * 512 + gx);
        yv = *reinterpret_cast<const float2*>(yp + gy * 512 + gx);
      }
      h2_t hx; hx.x = (_Float16)xv.x; hx.y = (_Float16)xv.y;
      h2_t hy; hy.x = (_Float16)yv.x; hy.y = (_Float16)yv.y;
      int si = (row * PAW + cp * 2) ^ ((row & 7) << 3);   // h2-safe: XOR bits>=3
      *reinterpret_cast<h2_t*>(xt + si) = hx;
      *reinterpret_cast<h2_t*>(xt + TILE + si) = hy;
    }
    __syncthreads();
    do_sigma_m<false>(0, frh, U, xt, hb, PIcs, gl1s, tid);
    do_sigma_m<false>(1, frh, U, xt, hb, PIcs, gl1s, tid);
    do_sigma_m<false>(2, frh, U, xt, hb, PIcs, gl1s, tid);
    do_sigma_m<false>(3, frh, U, xt, hb, PIcs, gl1s, tid);
    do_sigma_m<true >(4, frh, U, xt, hb, PIcs, gl1s, tid);
    // do_sigma ends with __syncthreads(): safe to restage next channel
  }

  float s = ((1.f - kALPHA) / 3.f) * gl1s;
#pragma unroll
  for (int i = 0; i < 8; ++i) s += kALPHA * (1.f - PIcs[i]);
#pragma unroll
  for (int off = 32; off > 0; off >>= 1) s += __shfl_down(s, off);
  if ((tid & 63) == 0) red[tid >> 6] = s;
  __syncthreads();
  if (tid == 0)
    atomicAdd(out, (red[0] + red[1] + red[2] + red[3]) *
                       (200.0f / (8.0f * 512.0f * 512.0f)));
}

extern "C" void kernel_launch(void* const* d_in, const int* in_sizes, int n_in,
                              void* d_out, int out_size, void* d_ws, size_t ws_size,
                              hipStream_t stream) {
  const float* x = (const float*)d_in[0];
  const float* y = (const float*)d_in[1];
  const float* gm = (const float*)d_in[2];
  float* out = (float*)d_out;
  float* ws = (float*)d_ws;   // 165 f32 + U + 20 KB weight frags

  hipMemsetAsync(d_out, 0, out_size * sizeof(float), stream);
  prep_k<<<1, 256, 0, stream>>>(gm, ws);
  msloss_k<<<dim3(8, 16, 8), 256, 0, stream>>>(x, y, ws, out);
}

// Round 15
// 281.665 us; speedup vs baseline: 1.4309x; 1.0597x over previous
//
#include <hip/hip_runtime.h>

typedef _Float16 h2_t __attribute__((ext_vector_type(2)));
typedef _Float16 f16x8 __attribute__((ext_vector_type(8)));
typedef float f32x4 __attribute__((ext_vector_type(4)));
typedef unsigned u32x4 __attribute__((ext_vector_type(4)));

#define DI __device__ __forceinline__

#if __has_builtin(__builtin_amdgcn_sched_barrier)
#define SCHED_FENCE() __builtin_amdgcn_sched_barrier(0)
#else
#define SCHED_FENCE()
#endif

constexpr int PAW = 96;          // xt pitch (halfs): 192 B rows, 16B-aligned + XOR swizzle
constexpr int PBV = 72;          // hb pitch (halfs): 144 B rows = 9*16 -> b128-aligned
constexpr int TILE = 64 * PAW;   // one staged image plane: 6144 halfs
constexpr int PLANE = 64 * PBV;  // one hb plane: 4608 halfs
constexpr float kC1 = 1.0e-4f;   // (0.01*1)^2
constexpr float kC2 = 9.0e-4f;   // (0.03*1)^2
constexpr float kALPHA = 0.025f;

DI float rcp_fast(float v) { return __builtin_amdgcn_rcpf(v); }

DI float fdot2f(h2_t a, h2_t b, float c) {
#if __has_builtin(__builtin_amdgcn_fdot2)
  return __builtin_amdgcn_fdot2(a, b, c, false);   // v_dot2_f32_f16
#else
  return c + (float)(a.x) * (float)(b.x) + (float)(a.y) * (float)(b.y);
#endif
}

DI h2_t w2h(unsigned u) { return __builtin_bit_cast(h2_t, u); }

DI f16x8 ldfrag(const _Float16* __restrict__ p) {
  return *reinterpret_cast<const f16x8*>(p);
}

DI f32x4 mfma16(f16x8 a, f16x8 b, f32x4 c) {
  return __builtin_amdgcn_mfma_f32_16x16x32_f16(a, b, c, 0, 0, 0);
}

DI f16x8 pkabs8(f16x8 v) {
  u32x4 u = __builtin_bit_cast(u32x4, v);
  u32x4 msk = {0x7FFF7FFFu, 0x7FFF7FFFu, 0x7FFF7FFFu, 0x7FFF7FFFu};
  u &= msk;
  return __builtin_bit_cast(f16x8, u);
}

// ---- horizontal conv as MFMA, TWO fields per pass -> 2 hb planes ----
// D[col][row] = Wh(banded) x field^T.  PASS 0: {x, y}.  PASS 1: {x^2+y^2, x*y}.
// PASS 2: {|x-y|} -> plane 0 only.  nt outer, acc lifetime = one nt, store
// immediately + sched fence (R3 lesson: full unroll hoists 16 ds_reads and
// spills at the 256-VGPR cap).
template<int PASS>
DI void hconv_p(const _Float16* __restrict__ xt, _Float16* __restrict__ hb,
                f16x8 wA0, f16x8 wA1, int w, int lane) {
  const int q = lane >> 4, m = lane & 15;
  const int K0b = (w < 2) ? 0 : 32;
  const int cb = w * 16 + q * 4;
  f32x4 zero4 = {0.f, 0.f, 0.f, 0.f};
#pragma unroll
  for (int nt = 0; nt < 4; ++nt) {
    const int row = nt * 16 + m;
    const int base = row * PAW + K0b + q * 8;
    f32x4 a0 = zero4, a1 = zero4;
#pragma unroll
    for (int ks = 0; ks < 2; ++ks) {
      const f16x8 A = ks ? wA1 : wA0;
      const int idx = (base + ks * 32) ^ ((row & 7) << 3);
      f16x8 xv = ldfrag(xt + idx);
      f16x8 yv = ldfrag(xt + TILE + idx);
      if (PASS == 0) {
        a0 = mfma16(A, xv, a0);
        a1 = mfma16(A, yv, a1);
      } else if (PASS == 1) {
        a0 = mfma16(A, xv * xv + yv * yv, a0);   // v_pk_mul/fma_f16
        a1 = mfma16(A, xv * yv, a1);
      } else {
        a0 = mfma16(A, pkabs8(xv - yv), a0);
      }
    }
    // C/D layout (m89-verified): m = (lane>>4)*4 + reg, n = lane&15.
    _Float16* wp = hb + cb * PBV + nt * 16 + m;
#pragma unroll
    for (int j = 0; j < 4; ++j) {
      wp[j * PBV] = (_Float16)a0[j];
      if (PASS < 2) wp[PLANE + j * PBV] = (_Float16)a1[j];
    }
    SCHED_FENCE();
  }
}

// ---- vertical conv over both planes -> acc[2*pl+g] ----
// A = hb data (m = col, contiguous b128), B = weight frags (n = out-row group).
DI void vconv2(const _Float16* __restrict__ hb,
               f16x8 w00, f16x8 w01, f16x8 w10, f16x8 w11,
               int w, int lane, f32x4* __restrict__ acc) {
  const int q = lane >> 4, m = lane & 15;
  const int base = (w * 16 + m) * PBV + q * 8;
#pragma unroll
  for (int ks = 0; ks < 2; ++ks) {
    f16x8 B0 = ks ? w01 : w00;
    f16x8 B1 = ks ? w11 : w10;
#pragma unroll
    for (int pl = 0; pl < 2; ++pl) {
      f16x8 A = ldfrag(hb + pl * PLANE + base + ks * 32);
      acc[2 * pl]     = mfma16(A, B0, acc[2 * pl]);
      acc[2 * pl + 1] = mfma16(A, B1, acc[2 * pl + 1]);
    }
    SCHED_FENCE();
  }
}

// ---- vertical conv of |x-y| (plane 0) collapsed to scalar via uniform U ----
DI float vl1(const _Float16* __restrict__ hb, const unsigned* __restrict__ U,
             int col, int r0) {
  const _Float16* p0 = hb + col * PBV + r0;
  float s = 0.f;
#pragma unroll
  for (int p = 0; p < 20; ++p)
    s = fdot2f(w2h(U[p]), *reinterpret_cast<const h2_t*>(p0 + 2 * p), s);
  return s;
}

// Per sigma: p{x,y} | bar | vconv2 | bar | p{sq,xy} | bar | vconv2 + fold |
// bar  (+ LAST: p{l1} | bar | vl1 | bar).  2 hb planes -> 43.0 KB LDS.
// RESIDENCY TEST (R14 lesson): at 52.7 KB the 3rd block did NOT land even
// though 3x52.7 = 158 <= 160 KB -- hypothesis: LDS alloc granule (>=8 KB) or
// per-CU reservation eats the 5.6 KB slack.  At 43 KB, 3 blocks fit even
// with a 48-KB granule (144 <= 160).  If occupancy still ~22%, the occupancy
// axis is dead -> revert to R10 2-barrier structure and attack barrier cost.
template<bool LAST>
DI void do_sigma_m(int s, const _Float16* __restrict__ frh,
                   const unsigned* __restrict__ U,
                   const _Float16* __restrict__ xt, _Float16* __restrict__ hb,
                   float* __restrict__ PIcs, float& gl1s, int tid) {
  const int lane = tid & 63, w = tid >> 6;
  // weight frags [s][cls][ks][lane][8h]: shared between hconv (cls = w&1) and
  // vconv (cls = out-row group) because Delta0 = 32ks - 16cls in both.
  const f16x8* fr = reinterpret_cast<const f16x8*>(frh) + s * 256 + lane;
  f16x8 w00 = fr[0], w01 = fr[64], w10 = fr[128], w11 = fr[192];
  const bool odd = (w & 1);
  f16x8 wA0 = odd ? w10 : w00;
  f16x8 wA1 = odd ? w11 : w01;

  f32x4 zero4 = {0.f, 0.f, 0.f, 0.f};

  hconv_p<0>(xt, hb, wA0, wA1, w, lane);
  __syncthreads();
  f32x4 a1[4];                 // [0..1]=mux, [2..3]=muy (per row-group)
#pragma unroll
  for (int i = 0; i < 4; ++i) a1[i] = zero4;
  vconv2(hb, w00, w01, w10, w11, w, lane, a1);
  __syncthreads();
  hconv_p<1>(xt, hb, wA0, wA1, w, lane);
  __syncthreads();
  f32x4 a2[4];                 // [0..1]=s2, [2..3]=exy
#pragma unroll
  for (int i = 0; i < 4; ++i) a2[i] = zero4;
  vconv2(hb, w00, w01, w10, w11, w, lane, a2);
  // fold
#pragma unroll
  for (int h = 0; h < 2; ++h)
#pragma unroll
    for (int j = 0; j < 4; ++j) {
      const int i = h * 4 + j;
      float a = a1[h][j], b = a1[2 + h][j];
      float m2 = a * a + b * b, mxy = a * b;
      PIcs[i] *= fmaf(2.f, a2[2 + h][j] - mxy, kC2) *
                 rcp_fast(a2[h][j] - m2 + kC2);
      if (LAST)                            // luminance folded into PIcs
        PIcs[i] *= fmaf(2.f, mxy, kC1) * rcp_fast(m2 + kC1);
    }
  __syncthreads();                         // hb free
  if (LAST) {
    hconv_p<2>(xt, hb, wA0, wA1, w, lane);
    __syncthreads();
    gl1s += vl1(hb, U, lane, w * 8);
    __syncthreads();
  }
}

DI unsigned packh(float a, float b) {
  h2_t v; v.x = (_Float16)a; v.y = (_Float16)b;
  return __builtin_bit_cast(unsigned, v);
}

// ws layout (floats): [0..164] f32 1D kernels; u32 U[20] @168; weight frags
// (halfs) @208: [sigma][cls][ks][lane][8] = 10240 halfs (~20 KB).
__global__ void prep_k(const float* __restrict__ gm, float* __restrict__ ws) {
  int t = threadIdx.x;
  if (t < 165) {
    int s = t / 33, j = t % 33;
    const float* mk = gm + (3 * s) * (33 * 33);
    ws[t] = mk[16 * 33 + j] / sqrtf(mk[16 * 33 + 16]);
  }
  __syncthreads();
  if (t == 0) {
    // U[p] = sum over i=0..3, j=p-i in [0,16] of (E[j]+O[j]) halves, sigma=8
    const float* w = ws + 4 * 33;
    unsigned* U = (unsigned*)(ws + 168);
    for (int p = 0; p < 20; ++p) {
      float ux = 0.f, uy = 0.f;
      for (int i = 0; i < 4; ++i) {
        int j = p - i;
        if (j < 0 || j > 16) continue;
        ux += w[2 * j];
        if (2 * j + 1 <= 32) uy += w[2 * j + 1];
        if (j > 0) ux += w[2 * j - 1];
        uy += w[2 * j];
      }
      U[p] = packh(ux, uy);
    }
  }
  // weight fragments; k-map k = K0 + 8*(lane>>4) + i applied identically to the
  // data-operand reads, so any bijective mis-guess of the HW k-map cancels.
  _Float16* fr = (_Float16*)(ws + 208);
  const int Rs[5] = {4, 6, 12, 16, 16};
  for (int e = t; e < 10240; e += 256) {
    int s = e >> 11, r = e & 2047;
    int cls = (r >> 10) & 1, ks = (r >> 9) & 1, lane = (r >> 3) & 63, i = r & 7;
    int tp = 32 * ks - 16 * cls + 8 * (lane >> 4) + i - (lane & 15);
    int R = Rs[s], j = tp - 16 + R;
    float v = (j >= 0 && j <= 2 * R) ? ws[s * 33 + j] : 0.f;
    fr[e] = (_Float16)v;
  }
}

// 64x32 output tile, 2 hb planes: 43.0 KB LDS -> 3 blocks/CU even under an
// 8-16 KB LDS alloc granule.  (256,2): natural VGPR alloc (~128); NEVER
// (256,3) -- twice measured (R2, R11) it caps at 84 VGPR and spills 300-700MB.
__global__ __launch_bounds__(256, 2)
void msloss_k(const float* __restrict__ x, const float* __restrict__ y,
              const float* __restrict__ ws, float* __restrict__ out) {
  // xt @0 [row][col] swizzled (64x96), yt @TILE, hb @2*TILE: 2 planes [col][row]
  __shared__ __align__(16) _Float16 smem[2 * TILE + 2 * PLANE];
  __shared__ float red[4];
  _Float16* xt = smem;
  _Float16* hb = smem + 2 * TILE;
  const _Float16* frh = (const _Float16*)(ws + 208);
  const unsigned* U = (const unsigned*)(ws + 168);
  const int tid = threadIdx.x;
  const int ox = blockIdx.x * 64, oy = blockIdx.y * 32;
  const int b = blockIdx.z;

  float PIcs[8];
  float gl1s = 0.f;
#pragma unroll
  for (int i = 0; i < 8; ++i) PIcs[i] = 1.f;

  for (int c = 0; c < 3; ++c) {
    const float* xp = x + (size_t)(b * 3 + c) * (512 * 512);
    const float* yp = y + (size_t)(b * 3 + c) * (512 * 512);
    // stage 64 rows x 96 cols fp32 -> fp16, swizzled [row][col], zero halo
#pragma unroll
    for (int it = 0; it < 12; ++it) {
      int idx = it * 256 + tid;            // 64 rows x 48 colpairs
      int row = idx / 48, cp = idx % 48;
      int gy = oy + row - 16, gx = ox + cp * 2 - 16;
      bool ok = ((unsigned)gy < 512u) && ((unsigned)gx < 512u);  // gx even
      float2 xv = make_float2(0.f, 0.f), yv = make_float2(0.f, 0.f);
      if (ok) {
        xv = *reinterpret_cast<const float2*>(xp + gy * 512 + gx);
        yv = *reinterpret_cast<const float2*>(yp + gy * 512 + gx);
      }
      h2_t hx; hx.x = (_Float16)xv.x; hx.y = (_Float16)xv.y;
      h2_t hy; hy.x = (_Float16)yv.x; hy.y = (_Float16)yv.y;
      int si = (row * PAW + cp * 2) ^ ((row & 7) << 3);   // h2-safe: XOR bits>=3
      *reinterpret_cast<h2_t*>(xt + si) = hx;
      *reinterpret_cast<h2_t*>(xt + TILE + si) = hy;
    }
    __syncthreads();
    do_sigma_m<false>(0, frh, U, xt, hb, PIcs, gl1s, tid);
    do_sigma_m<false>(1, frh, U, xt, hb, PIcs, gl1s, tid);
    do_sigma_m<false>(2, frh, U, xt, hb, PIcs, gl1s, tid);
    do_sigma_m<false>(3, frh, U, xt, hb, PIcs, gl1s, tid);
    do_sigma_m<true >(4, frh, U, xt, hb, PIcs, gl1s, tid);
    // do_sigma ends with __syncthreads(): safe to restage next channel
  }

  float s = ((1.f - kALPHA) / 3.f) * gl1s;
#pragma unroll
  for (int i = 0; i < 8; ++i) s += kALPHA * (1.f - PIcs[i]);
#pragma unroll
  for (int off = 32; off > 0; off >>= 1) s += __shfl_down(s, off);
  if ((tid & 63) == 0) red[tid >> 6] = s;
  __syncthreads();
  if (tid == 0)
    atomicAdd(out, (red[0] + red[1] + red[2] + red[3]) *
                       (200.0f / (8.0f * 512.0f * 512.0f)));
}

extern "C" void kernel_launch(void* const* d_in, const int* in_sizes, int n_in,
                              void* d_out, int out_size, void* d_ws, size_t ws_size,
                              hipStream_t stream) {
  const float* x = (const float*)d_in[0];
  const float* y = (const float*)d_in[1];
  const float* gm = (const float*)d_in[2];
  float* out = (float*)d_out;
  float* ws = (float*)d_ws;   // 165 f32 + U + 20 KB weight frags

  hipMemsetAsync(d_out, 0, out_size * sizeof(float), stream);
  prep_k<<<1, 256, 0, stream>>>(gm, ws);
  msloss_k<<<dim3(8, 16, 8), 256, 0, stream>>>(x, y, ws, out);
}

// Round 16
// 270.899 us; speedup vs baseline: 1.4877x; 1.0397x over previous
//
#include <hip/hip_runtime.h>

typedef _Float16 h2_t __attribute__((ext_vector_type(2)));
typedef _Float16 h4_t __attribute__((ext_vector_type(4)));
typedef _Float16 f16x8 __attribute__((ext_vector_type(8)));
typedef float f32x4 __attribute__((ext_vector_type(4)));
typedef unsigned u32x4 __attribute__((ext_vector_type(4)));

#define DI __device__ __forceinline__

#if __has_builtin(__builtin_amdgcn_sched_barrier)
#define SCHED_FENCE() __builtin_amdgcn_sched_barrier(0)
#else
#define SCHED_FENCE()
#endif

constexpr int PAW = 96;          // xt pitch (halfs): 192 B rows, 16B-aligned + XOR swizzle
constexpr int PBV = 72;          // hb pitch (halfs): 144 B rows = 9*16 -> b64/b128-aligned
constexpr int TILE = 64 * PAW;   // one staged image plane: 6144 halfs
constexpr int PLANE = 64 * PBV;  // one hb plane: 4608 halfs
constexpr float kC1 = 1.0e-4f;   // (0.01*1)^2
constexpr float kC2 = 9.0e-4f;   // (0.03*1)^2
constexpr float kALPHA = 0.025f;

DI float rcp_fast(float v) { return __builtin_amdgcn_rcpf(v); }

DI float fdot2f(h2_t a, h2_t b, float c) {
#if __has_builtin(__builtin_amdgcn_fdot2)
  return __builtin_amdgcn_fdot2(a, b, c, false);   // v_dot2_f32_f16
#else
  return c + (float)(a.x) * (float)(b.x) + (float)(a.y) * (float)(b.y);
#endif
}

DI h2_t w2h(unsigned u) { return __builtin_bit_cast(h2_t, u); }

DI f16x8 ldfrag(const _Float16* __restrict__ p) {
  return *reinterpret_cast<const f16x8*>(p);
}

DI f32x4 mfma16(f16x8 a, f16x8 b, f32x4 c) {
  return __builtin_amdgcn_mfma_f32_16x16x32_f16(a, b, c, 0, 0, 0);
}

DI f16x8 pkabs8(f16x8 v) {
  u32x4 u = __builtin_bit_cast(u32x4, v);
  u32x4 msk = {0x7FFF7FFFu, 0x7FFF7FFFu, 0x7FFF7FFFu, 0x7FFF7FFFu};
  u &= msk;
  return __builtin_bit_cast(f16x8, u);
}

DI h4_t pack4(f32x4 v) {
  h4_t r;
  r.x = (_Float16)v[0]; r.y = (_Float16)v[1];
  r.z = (_Float16)v[2]; r.w = (_Float16)v[3];
  return r;
}

// ---- fused horizontal conv, OPERAND-SWAPPED: D = X * Wh^T ----
// A = data fragments (m = data row), B = weight frags (n = out-col).
// Fields {x, y, x^2+y^2, x*y (,|x-y|)} -> planes 0..3 (,4), all from ONE set
// of xt/yt reads.  C/D: n = lane&15 -> outcol w*16+l15; m = q*4+j -> rows
// nt*16+q*4+j are CONTIGUOUS in hb[col][row] -> one ds_write_b64 per plane
// (was 4x ds_write_b16: R10's 64-80 scalar stores/sigma were ~33% of the
// LDS pipe).  Data-as-A and weights-as-B roles are the ones already
// HW-verified in vconv (absmax 0.0 since R3); weight table unchanged (tp
// depends only on k - (lane&15), symmetric between m/n roles).
// nt outer, acc lifetime = one nt + sched fence (R3 lesson).
template<bool L1P>
DI void hconv_all(const _Float16* __restrict__ xt, _Float16* __restrict__ hb,
                  f16x8 wB0, f16x8 wB1, int w, int lane) {
  const int q = lane >> 4, l15 = lane & 15;
  const int K0b = (w < 2) ? 0 : 32;
  f32x4 zero4 = {0.f, 0.f, 0.f, 0.f};
#pragma unroll
  for (int nt = 0; nt < 4; ++nt) {
    const int row = nt * 16 + l15;           // A-frag m-index = data row
    const int base = row * PAW + K0b + q * 8;
    f32x4 ax = zero4, ay = zero4, asq = zero4, axy = zero4, al1 = zero4;
#pragma unroll
    for (int ks = 0; ks < 2; ++ks) {
      const f16x8 B = ks ? wB1 : wB0;
      const int idx = (base + ks * 32) ^ ((row & 7) << 3);
      f16x8 xv = ldfrag(xt + idx);
      f16x8 yv = ldfrag(xt + TILE + idx);
      ax = mfma16(xv, B, ax);
      ay = mfma16(yv, B, ay);
      asq = mfma16(xv * xv + yv * yv, B, asq);   // v_pk_mul/fma_f16
      axy = mfma16(xv * yv, B, axy);
      if (L1P) al1 = mfma16(pkabs8(xv - yv), B, al1);
    }
    // rows nt*16 + q*4 + j, j=0..3 contiguous -> b64 store per plane
    _Float16* wp = hb + (w * 16 + l15) * PBV + nt * 16 + q * 4;
    *reinterpret_cast<h4_t*>(wp) = pack4(ax);
    *reinterpret_cast<h4_t*>(wp + PLANE) = pack4(ay);
    *reinterpret_cast<h4_t*>(wp + 2 * PLANE) = pack4(asq);
    *reinterpret_cast<h4_t*>(wp + 3 * PLANE) = pack4(axy);
    if (L1P) *reinterpret_cast<h4_t*>(wp + 4 * PLANE) = pack4(al1);
    SCHED_FENCE();
  }
}

// ---- fused vertical conv: all 4 stat planes -> 8 f32x4 accumulators ----
// A = hb data (m = col, contiguous b128 along rows), B = weight frags
// (n = out-row 16-group).  acc[2*pl + g].  Stats live only in this region.
DI void vconv_all(const _Float16* __restrict__ hb,
                  f16x8 w00, f16x8 w01, f16x8 w10, f16x8 w11,
                  int w, int lane, f32x4* __restrict__ acc) {
  const int q = lane >> 4, m = lane & 15;
  const int base = (w * 16 + m) * PBV + q * 8;
#pragma unroll
  for (int ks = 0; ks < 2; ++ks) {
    f16x8 B0 = ks ? w01 : w00;
    f16x8 B1 = ks ? w11 : w10;
#pragma unroll
    for (int pl = 0; pl < 4; ++pl) {
      f16x8 A = ldfrag(hb + pl * PLANE + base + ks * 32);
      acc[2 * pl]     = mfma16(A, B0, acc[2 * pl]);
      acc[2 * pl + 1] = mfma16(A, B1, acc[2 * pl + 1]);
    }
    SCHED_FENCE();
  }
}

// ---- vertical conv of |x-y| (plane 4) collapsed to scalar via uniform U ----
DI float vl1(const _Float16* __restrict__ hb, const unsigned* __restrict__ U,
             int col, int r0) {
  const _Float16* p0 = hb + 4 * PLANE + col * PBV + r0;
  float s = 0.f;
#pragma unroll
  for (int p = 0; p < 20; ++p)
    s = fdot2f(w2h(U[p]), *reinterpret_cast<const h2_t*>(p0 + 2 * p), s);
  return s;
}

// Per sigma: hconv_all | bar | vconv_all + fold (+vl1) | bar -- the R10
// 2-barrier structure (best measured, 199 us).  R14/R15 proved the occupancy
// axis dead (3rd block never lands regardless of LDS; extra barriers cost
// 14-19%), so: 5 planes, 2 barriers, and attack instruction count instead.
template<bool LAST>
DI void do_sigma_m(int s, const _Float16* __restrict__ frh,
                   const unsigned* __restrict__ U,
                   const _Float16* __restrict__ xt, _Float16* __restrict__ hb,
                   float* __restrict__ PIcs, float& gl1s, int tid) {
  const int lane = tid & 63, w = tid >> 6;
  // weight frags [s][cls][ks][lane][8h]: shared between hconv (cls = w&1) and
  // vconv (cls = out-row group) because tp = 32ks - 16cls + k - (lane&15).
  const f16x8* fr = reinterpret_cast<const f16x8*>(frh) + s * 256 + lane;
  f16x8 w00 = fr[0], w01 = fr[64], w10 = fr[128], w11 = fr[192];
  const bool odd = (w & 1);
  f16x8 wB0 = odd ? w10 : w00;
  f16x8 wB1 = odd ? w11 : w01;

  hconv_all<LAST>(xt, hb, wB0, wB1, w, lane);
  __syncthreads();
  f32x4 zero4 = {0.f, 0.f, 0.f, 0.f};
  f32x4 acc[8];
#pragma unroll
  for (int i = 0; i < 8; ++i) acc[i] = zero4;
  vconv_all(hb, w00, w01, w10, w11, w, lane, acc);
  if (LAST) gl1s += vl1(hb, U, tid & 63, (tid >> 6) * 8);
  // fold: acc[0..1]=mux, [2..3]=muy, [4..5]=s2, [6..7]=exy (per row-group h)
#pragma unroll
  for (int h = 0; h < 2; ++h)
#pragma unroll
    for (int j = 0; j < 4; ++j) {
      const int i = h * 4 + j;
      float a = acc[h][j], b = acc[2 + h][j];
      float m2 = a * a + b * b, mxy = a * b;
      PIcs[i] *= fmaf(2.f, acc[6 + h][j] - mxy, kC2) *
                 rcp_fast(acc[4 + h][j] - m2 + kC2);
      if (LAST)                            // luminance folded into PIcs
        PIcs[i] *= fmaf(2.f, mxy, kC1) * rcp_fast(m2 + kC1);
    }
  __syncthreads();                         // hb free for next sigma/channel
}

DI unsigned packh(float a, float b) {
  h2_t v; v.x = (_Float16)a; v.y = (_Float16)b;
  return __builtin_bit_cast(unsigned, v);
}

// ws layout (floats): [0..164] f32 1D kernels; u32 U[20] @168; weight frags
// (halfs) @208: [sigma][cls][ks][lane][8] = 10240 halfs (~20 KB).
__global__ void prep_k(const float* __restrict__ gm, float* __restrict__ ws) {
  int t = threadIdx.x;
  if (t < 165) {
    int s = t / 33, j = t % 33;
    const float* mk = gm + (3 * s) * (33 * 33);
    ws[t] = mk[16 * 33 + j] / sqrtf(mk[16 * 33 + 16]);
  }
  __syncthreads();
  if (t == 0) {
    // U[p] = sum over i=0..3, j=p-i in [0,16] of (E[j]+O[j]) halves, sigma=8
    const float* w = ws + 4 * 33;
    unsigned* U = (unsigned*)(ws + 168);
    for (int p = 0; p < 20; ++p) {
      float ux = 0.f, uy = 0.f;
      for (int i = 0; i < 4; ++i) {
        int j = p - i;
        if (j < 0 || j > 16) continue;
        ux += w[2 * j];
        if (2 * j + 1 <= 32) uy += w[2 * j + 1];
        if (j > 0) ux += w[2 * j - 1];
        uy += w[2 * j];
      }
      U[p] = packh(ux, uy);
    }
  }
  // weight fragments; k-map k = K0 + 8*(lane>>4) + i applied identically to the
  // data-operand reads, so any bijective mis-guess of the HW k-map cancels.
  _Float16* fr = (_Float16*)(ws + 208);
  const int Rs[5] = {4, 6, 12, 16, 16};
  for (int e = t; e < 10240; e += 256) {
    int s = e >> 11, r = e & 2047;
    int cls = (r >> 10) & 1, ks = (r >> 9) & 1, lane = (r >> 3) & 63, i = r & 7;
    int tp = 32 * ks - 16 * cls + 8 * (lane >> 4) + i - (lane & 15);
    int R = Rs[s], j = tp - 16 + R;
    float v = (j >= 0 && j <= 2 * R) ? ws[s * 33 + j] : 0.f;
    fr[e] = (_Float16)v;
  }
}

// 64x32 output tile, 5 hb planes: ~69.5 KB LDS, 2 blocks/CU (proven max).
// (256,2): natural VGPR alloc ~128.  NEVER (256,3) -- twice measured (R2,
// R11): allocator caps at 84 VGPR and spills 300-700 MB of scratch.
__global__ __launch_bounds__(256, 2)
void msloss_k(const float* __restrict__ x, const float* __restrict__ y,
              const float* __restrict__ ws, float* __restrict__ out) {
  // xt @0 [row][col] swizzled (64x96), yt @TILE, hb @2*TILE: 5 planes [col][row]
  __shared__ __align__(16) _Float16 smem[2 * TILE + 5 * PLANE];
  __shared__ float red[4];
  _Float16* xt = smem;
  _Float16* hb = smem + 2 * TILE;
  const _Float16* frh = (const _Float16*)(ws + 208);
  const unsigned* U = (const unsigned*)(ws + 168);
  const int tid = threadIdx.x;
  const int ox = blockIdx.x * 64, oy = blockIdx.y * 32;
  const int b = blockIdx.z;

  float PIcs[8];
  float gl1s = 0.f;
#pragma unroll
  for (int i = 0; i < 8; ++i) PIcs[i] = 1.f;

  for (int c = 0; c < 3; ++c) {
    const float* xp = x + (size_t)(b * 3 + c) * (512 * 512);
    const float* yp = y + (size_t)(b * 3 + c) * (512 * 512);
    // stage 64 rows x 96 cols fp32 -> fp16, swizzled [row][col], zero halo
#pragma unroll
    for (int it = 0; it < 12; ++it) {
      int idx = it * 256 + tid;            // 64 rows x 48 colpairs
      int row = idx / 48, cp = idx % 48;
      int gy = oy + row - 16, gx = ox + cp * 2 - 16;
      bool ok = ((unsigned)gy < 512u) && ((unsigned)gx < 512u);  // gx even
      float2 xv = make_float2(0.f, 0.f), yv = make_float2(0.f, 0.f);
      if (ok) {
        xv = *reinterpret_cast<const float2*>(xp + gy * 512 + gx);
        yv = *reinterpret_cast<const float2*>(yp + gy * 512 + gx);
      }
      h2_t hx; hx.x = (_Float16)xv.x; hx.y = (_Float16)xv.y;
      h2_t hy; hy.x = (_Float16)yv.x; hy.y = (_Float16)yv.y;
      int si = (row * PAW + cp * 2) ^ ((row & 7) << 3);   // h2-safe: XOR bits>=3
      *reinterpret_cast<h2_t*>(xt + si) = hx;
      *reinterpret_cast<h2_t*>(xt + TILE + si) = hy;
    }
    __syncthreads();
    do_sigma_m<false>(0, frh, U, xt, hb, PIcs, gl1s, tid);
    do_sigma_m<false>(1, frh, U, xt, hb, PIcs, gl1s, tid);
    do_sigma_m<false>(2, frh, U, xt, hb, PIcs, gl1s, tid);
    do_sigma_m<false>(3, frh, U, xt, hb, PIcs, gl1s, tid);
    do_sigma_m<true >(4, frh, U, xt, hb, PIcs, gl1s, tid);
    // do_sigma ends with __syncthreads(): safe to restage next channel
  }

  float s = ((1.f - kALPHA) / 3.f) * gl1s;
#pragma unroll
  for (int i = 0; i < 8; ++i) s += kALPHA * (1.f - PIcs[i]);
#pragma unroll
  for (int off = 32; off > 0; off >>= 1) s += __shfl_down(s, off);
  if ((tid & 63) == 0) red[tid >> 6] = s;
  __syncthreads();
  if (tid == 0)
    atomicAdd(out, (red[0] + red[1] + red[2] + red[3]) *
                       (200.0f / (8.0f * 512.0f * 512.0f)));
}

extern "C" void kernel_launch(void* const* d_in, const int* in_sizes, int n_in,
                              void* d_out, int out_size, void* d_ws, size_t ws_size,
                              hipStream_t stream) {
  const float* x = (const float*)d_in[0];
  const float* y = (const float*)d_in[1];
  const float* gm = (const float*)d_in[2];
  float* out = (float*)d_out;
  float* ws = (float*)d_ws;   // 165 f32 + U + 20 KB weight frags

  hipMemsetAsync(d_out, 0, out_size * sizeof(float), stream);
  prep_k<<<1, 256, 0, stream>>>(gm, ws);
  msloss_k<<<dim3(8, 16, 8), 256, 0, stream>>>(x, y, ws, out);
}